// Round 1
// baseline (333.775 us; speedup 1.0000x reference)
//
#include <hip/hip_runtime.h>
#include <math.h>

#define B_    16
#define S_    512
#define D_    768
#define L_    5
#define MAXW  5
#define TOPK  8
#define NSPAN (S_*MAXW)    // 2560
#define M_    (B_*S_)      // 8192

// ---------------------------------------------------------------------------
// Main GEMM: out(8192x768) = T(8192x768) @ W(768x768), two weight halves in
// one grid: blockIdx.y<6 -> A (W1 top), else -> Bm (W1 bottom).
// 128x128 tile, BK=16, 256 threads, 8x8 per thread. fp32 VALU.
// ---------------------------------------------------------------------------
__global__ __launch_bounds__(256, 3)
void gemm_k(const float* __restrict__ Tm, const float* __restrict__ W1,
            float* __restrict__ Aout, float* __restrict__ Bout) {
    constexpr int K = D_, N = D_;
    __shared__ float As[16][128];   // k-major (transposed A tile)
    __shared__ float Bs[16][128];

    const int bm  = blockIdx.x;           // 0..63
    const int bn2 = blockIdx.y;           // 0..11
    const float* W = W1 + (bn2 >= 6 ? (size_t)D_ * D_ : 0);
    float* Om      = (bn2 >= 6) ? Bout : Aout;
    const int bn   = (bn2 >= 6) ? bn2 - 6 : bn2;

    const int tid = threadIdx.x;
    const int row0 = bm * 128, col0 = bn * 128;
    const int tx = tid & 15, ty = tid >> 4;

    float acc[8][8];
    #pragma unroll
    for (int i = 0; i < 8; ++i)
        #pragma unroll
        for (int j = 0; j < 8; ++j) acc[i][j] = 0.f;

    const int arow = tid >> 1;            // 0..127
    const int acol = (tid & 1) * 4;       // 0 or 4
    const int brow = tid >> 5;            // 0..7
    const int bcol = (tid & 31) * 4;      // 0..124

    const float* Aptr = Tm + (size_t)(row0 + arow) * K + acol;
    const float* Bptr = W  + (size_t)brow * N + col0 + bcol;

    for (int k0 = 0; k0 < K; k0 += 16) {
        // stage A tile (128 rows x 16 k), transposed into As[k][m]
        #pragma unroll
        for (int r = 0; r < 2; ++r) {
            float4 av = *reinterpret_cast<const float4*>(Aptr + k0 + r * 8);
            As[acol + r*8 + 0][arow] = av.x;
            As[acol + r*8 + 1][arow] = av.y;
            As[acol + r*8 + 2][arow] = av.z;
            As[acol + r*8 + 3][arow] = av.w;
        }
        // stage B tile (16 k x 128 cols)
        #pragma unroll
        for (int r = 0; r < 2; ++r) {
            float4 bv = *reinterpret_cast<const float4*>(Bptr + (size_t)(k0 + r*8) * N);
            *reinterpret_cast<float4*>(&Bs[brow + r*8][bcol]) = bv;
        }
        __syncthreads();
        #pragma unroll
        for (int k = 0; k < 16; ++k) {
            float a[8], b[8];
            *reinterpret_cast<float4*>(&a[0]) = *reinterpret_cast<const float4*>(&As[k][ty*8]);
            *reinterpret_cast<float4*>(&a[4]) = *reinterpret_cast<const float4*>(&As[k][ty*8+4]);
            *reinterpret_cast<float4*>(&b[0]) = *reinterpret_cast<const float4*>(&Bs[k][tx*4]);
            *reinterpret_cast<float4*>(&b[4]) = *reinterpret_cast<const float4*>(&Bs[k][tx*4+64]);
            #pragma unroll
            for (int i = 0; i < 8; ++i)
                #pragma unroll
                for (int j = 0; j < 8; ++j)
                    acc[i][j] = fmaf(a[i], b[j], acc[i][j]);
        }
        __syncthreads();
    }
    #pragma unroll
    for (int i = 0; i < 8; ++i) {
        size_t ro = (size_t)(row0 + ty*8 + i) * N + col0;
        float4 v0 = make_float4(acc[i][0], acc[i][1], acc[i][2], acc[i][3]);
        float4 v1 = make_float4(acc[i][4], acc[i][5], acc[i][6], acc[i][7]);
        *reinterpret_cast<float4*>(&Om[ro + tx*4])      = v0;
        *reinterpret_cast<float4*>(&Om[ro + tx*4 + 64]) = v1;
    }
}

// ---------------------------------------------------------------------------
// w2ws[d] = sum_e W2[d,e]*Ws[e];  block 768 computes c = dot(b2,Ws)+bs
// ---------------------------------------------------------------------------
__global__ void w2ws_k(const float* __restrict__ W2, const float* __restrict__ Ws,
                       const float* __restrict__ b2, const float* __restrict__ bs,
                       float* __restrict__ w2ws, float* __restrict__ cc) {
    const int d = blockIdx.x;
    const int lane = threadIdx.x;           // 64 threads
    float p = 0.f;
    if (d < D_) {
        const float* row = W2 + (size_t)d * D_;
        for (int i = lane; i < D_; i += 64) p += row[i] * Ws[i];
    } else {
        for (int i = lane; i < D_; i += 64) p += b2[i] * Ws[i];
    }
    #pragma unroll
    for (int off = 32; off; off >>= 1) p += __shfl_xor(p, off);
    if (lane == 0) {
        if (d < D_) w2ws[d] = p;
        else        *cc = p + *bs;
    }
}

__global__ void seqlen_k(const int* __restrict__ mask, int* __restrict__ seqlen) {
    const int b = blockIdx.x;
    const int lane = threadIdx.x;           // 64 threads
    int p = 0;
    for (int i = lane; i < S_; i += 64) p += mask[b * S_ + i];
    #pragma unroll
    for (int off = 32; off; off >>= 1) p += __shfl_xor(p, off);
    if (lane == 0) seqlen[b] = p;
}

// ---------------------------------------------------------------------------
// span scores: one 64-thread block per (b,s); computes 5 window scores
// ---------------------------------------------------------------------------
__global__ __launch_bounds__(64)
void score_k(const float* __restrict__ A, const float* __restrict__ Bm,
             const float* __restrict__ b1, const float* __restrict__ w2ws,
             const float* __restrict__ cc, const int* __restrict__ seqlen,
             float* __restrict__ scores) {
    const int bsid = blockIdx.x;            // b*S + s
    const int b = bsid >> 9, s = bsid & 511;
    const int lane = threadIdx.x;
    float a[12], w[12], bb[12];
    const float* Arow = A + (size_t)bsid * D_;
    #pragma unroll
    for (int i = 0; i < 12; ++i) {
        int d = lane + i * 64;
        a[i]  = Arow[d];
        w[i]  = w2ws[d];
        bb[i] = b1[d];
    }
    const int sl = seqlen[b];
    const float c = *cc;
    #pragma unroll
    for (int w_ = 0; w_ < MAXW; ++w_) {
        const int e = min(s + w_, S_ - 1);
        const float* Brow = Bm + ((size_t)(b << 9) + e) * D_;
        float p = 0.f;
        #pragma unroll
        for (int i = 0; i < 12; ++i) {
            float h = a[i] + Brow[lane + i * 64] + bb[i];
            p = fmaf(fmaxf(h, 0.f), w[i], p);
        }
        #pragma unroll
        for (int off = 32; off; off >>= 1) p += __shfl_xor(p, off);
        if (lane == 0)
            scores[b * NSPAN + s * MAXW + w_] = (s + w_ < sl) ? (p + c) : -1e30f;
    }
}

// ---------------------------------------------------------------------------
// top-k (k=8) per batch, iterative argmax, tie -> lowest index (matches lax.top_k)
// ---------------------------------------------------------------------------
__global__ __launch_bounds__(256)
void topk_k(const float* __restrict__ scores, float* __restrict__ top_rel,
            int* __restrict__ top_idx) {
    __shared__ float sv[NSPAN];
    __shared__ float rv[4];
    __shared__ int   ri[4];
    const int b = blockIdx.x, tid = threadIdx.x;
    for (int i = tid; i < NSPAN; i += 256) sv[i] = scores[b * NSPAN + i];
    __syncthreads();
    for (int k = 0; k < TOPK; ++k) {
        float best = -INFINITY; int bi = 1 << 30;
        for (int i = tid; i < NSPAN; i += 256) {
            float v = sv[i];
            if (v > best || (v == best && i < bi)) { best = v; bi = i; }
        }
        #pragma unroll
        for (int off = 32; off; off >>= 1) {
            float ov = __shfl_xor(best, off);
            int   oi = __shfl_xor(bi, off);
            if (ov > best || (ov == best && oi < bi)) { best = ov; bi = oi; }
        }
        if ((tid & 63) == 0) { rv[tid >> 6] = best; ri[tid >> 6] = bi; }
        __syncthreads();
        if (tid == 0) {
            #pragma unroll
            for (int wv = 1; wv < 4; ++wv)
                if (rv[wv] > best || (rv[wv] == best && ri[wv] < bi)) { best = rv[wv]; bi = ri[wv]; }
            top_rel[b * TOPK + k] = best;
            top_idx[b * TOPK + k] = bi;
            sv[bi] = -INFINITY;
        }
        __syncthreads();
    }
}

// ---------------------------------------------------------------------------
// full span_repr for top-k spans + sim against labels. one block per (b,k)
// ---------------------------------------------------------------------------
__global__ __launch_bounds__(256)
void repr_k(const float* __restrict__ A, const float* __restrict__ Bm,
            const float* __restrict__ b1, const float* __restrict__ W2,
            const float* __restrict__ b2, const float* __restrict__ labels,
            const int* __restrict__ top_idx, float* __restrict__ sim) {
    const int blk = blockIdx.x;
    const int b = blk >> 3, k = blk & 7;
    const int tid = threadIdx.x;
    __shared__ float h[D_];
    __shared__ float sr[D_];
    __shared__ float red[4];

    const int n = top_idx[b * TOPK + k];
    const int s = n / MAXW, w = n % MAXW;
    const int e = min(s + w, S_ - 1);
    const float* Arow = A  + (size_t)(b * S_ + s) * D_;
    const float* Brow = Bm + (size_t)(b * S_ + e) * D_;
    for (int d = tid; d < D_; d += 256) h[d] = fmaxf(Arow[d] + Brow[d] + b1[d], 0.f);
    __syncthreads();

    float r0 = b2[tid], r1 = b2[tid + 256], r2 = b2[tid + 512];
    for (int d = 0; d < D_; ++d) {
        const float hv = h[d];
        const float* Wrow = W2 + (size_t)d * D_;
        r0 = fmaf(hv, Wrow[tid],       r0);
        r1 = fmaf(hv, Wrow[tid + 256], r1);
        r2 = fmaf(hv, Wrow[tid + 512], r2);
    }
    sr[tid] = r0; sr[tid + 256] = r1; sr[tid + 512] = r2;
    __syncthreads();

    const float* lab = labels + (size_t)b * L_ * D_;
    for (int l = 0; l < L_; ++l) {
        float p = 0.f;
        for (int d = tid; d < D_; d += 256) p = fmaf(lab[l * D_ + d], sr[d], p);
        #pragma unroll
        for (int off = 32; off; off >>= 1) p += __shfl_xor(p, off);
        if ((tid & 63) == 0) red[tid >> 6] = p;
        __syncthreads();
        if (tid == 0) sim[(b * L_ + l) * TOPK + k] = red[0] + red[1] + red[2] + red[3];
        __syncthreads();
    }
}

// ---------------------------------------------------------------------------
// softmax over top_rel, label_scores, sigmoid, write scores + mask
// ---------------------------------------------------------------------------
__global__ void final_k(const float* __restrict__ top_rel, const float* __restrict__ sim,
                        float* __restrict__ out) {
    const int b = blockIdx.x, tid = threadIdx.x;  // 64 threads
    float m = -INFINITY;
    #pragma unroll
    for (int k = 0; k < TOPK; ++k) m = fmaxf(m, top_rel[b * TOPK + k]);
    float wgt[TOPK]; float Z = 0.f;
    #pragma unroll
    for (int k = 0; k < TOPK; ++k) { wgt[k] = expf(top_rel[b * TOPK + k] - m); Z += wgt[k]; }
    if (tid < L_) {
        float acc = 0.f;
        #pragma unroll
        for (int k = 0; k < TOPK; ++k) acc += sim[(b * L_ + tid) * TOPK + k] * wgt[k];
        const float sc = acc / Z;
        out[b * L_ + tid]            = 1.f / (1.f + expf(-sc));
        out[B_ * L_ + b * L_ + tid]  = 1.0f;   // mask = True
    }
}

// ---------------------------------------------------------------------------
extern "C" void kernel_launch(void* const* d_in, const int* in_sizes, int n_in,
                              void* d_out, int out_size, void* d_ws, size_t ws_size,
                              hipStream_t stream) {
    const float* token_embs = (const float*)d_in[0];
    const int*   token_mask = (const int*)  d_in[1];
    const float* label_embs = (const float*)d_in[2];
    const float* W1 = (const float*)d_in[3];
    const float* b1 = (const float*)d_in[4];
    const float* W2 = (const float*)d_in[5];
    const float* b2 = (const float*)d_in[6];
    const float* Ws = (const float*)d_in[7];
    const float* bs = (const float*)d_in[8];
    float* out = (float*)d_out;

    float* A       = (float*)d_ws;                 // 8192*768
    float* Bm      = A + (size_t)M_ * D_;          // 8192*768
    float* scores  = Bm + (size_t)M_ * D_;         // 16*2560
    float* w2ws    = scores + B_ * NSPAN;          // 768
    float* cc      = w2ws + D_;                    // 1
    int*   seqlen  = (int*)(cc + 1);               // 16
    float* top_rel = (float*)(seqlen + B_);        // 128
    int*   top_idx = (int*)(top_rel + B_ * TOPK);  // 128
    float* sim     = (float*)(top_idx + B_ * TOPK);// 640

    gemm_k  <<<dim3(64, 12), 256, 0, stream>>>(token_embs, W1, A, Bm);
    w2ws_k  <<<D_ + 1, 64, 0, stream>>>(W2, Ws, b2, bs, w2ws, cc);
    seqlen_k<<<B_, 64, 0, stream>>>(token_mask, seqlen);
    score_k <<<M_, 64, 0, stream>>>(A, Bm, b1, w2ws, cc, seqlen, scores);
    topk_k  <<<B_, 256, 0, stream>>>(scores, top_rel, top_idx);
    repr_k  <<<B_ * TOPK, 256, 0, stream>>>(A, Bm, b1, W2, b2, label_embs, top_idx, sim);
    final_k <<<B_, 64, 0, stream>>>(top_rel, sim, out);
}